// Round 3
// baseline (168.682 us; speedup 1.0000x reference)
//
#include <hip/hip_runtime.h>

#define BDIM 128
#define CDIM 512
#define LIN  720
#define LOUT 336
#define BK   32
#define NSTAGES 23
#define NTHREADS 768        // 12 waves: 4 (M) x 3 (N)
#define A_BUF 4096          // ushorts: 4 k-octets * 128 rows * 8
#define B_BUF 10752         // ushorts: 4 k-octets * 336 cols * 8

typedef short v8s __attribute__((ext_vector_type(8)));  // 8 bf16
typedef float v4f __attribute__((ext_vector_type(4)));  // MFMA acc

__device__ __forceinline__ unsigned short f2bf(float f) {
    unsigned int u = __builtin_bit_cast(unsigned int, f);
    u += 0x7fffu + ((u >> 16) & 1u);
    return (unsigned short)(u >> 16);
}
__device__ __forceinline__ unsigned pk2(float lo, float hi) {
    return (unsigned)f2bf(lo) | ((unsigned)f2bf(hi) << 16);
}

__global__ __launch_bounds__(NTHREADS, 3)
void grouped_linear_kernel(const float* __restrict__ x,
                           const float* __restrict__ W,
                           const float* __restrict__ bias,
                           float* __restrict__ out)
{
    const int c    = blockIdx.x;
    const int tid  = threadIdx.x;
    const int lane = tid & 63;
    const int wave = tid >> 6;
    const int wr   = wave / 3;   // row tile 0..3 (32 rows each)
    const int wc   = wave % 3;   // col tile 0..2 (112 cols each)

    __shared__ unsigned short Alds[2 * A_BUF];   // 16 KB (double buffer)
    __shared__ unsigned short Blds[2 * B_BUF];   // 43 KB (double buffer)

    const float* xg = x + (size_t)c * LIN;
    const float* Wg = W + (size_t)c * LIN * LOUT;

    // ---- A staging tasks: 1024 float4/stage; task f: row=f>>3, kq=f&7.
    // task0 = tid (all threads); task1 = 768+(tid&255) (dup for tid>=256,
    // same value -> benign LDS write race, keeps loop branch-free).
    const int rowA0 = tid >> 3, kqA = tid & 7;
    const int rowA1 = (768 + (tid & 255)) >> 3;
    // ---- B staging tasks: 672 (168 n-pairs x 4 k-octets); dup last 96.
    const int tB   = (tid < 672) ? tid : (tid - 96);
    const int npB  = tB % 168;
    const int octB = tB / 168;
    const int n0B  = npB * 2;

    const int offA0 = ((kqA >> 1) * BDIM + rowA0) * 8 + (kqA & 1) * 4;
    const int offA1 = ((kqA >> 1) * BDIM + rowA1) * 8 + (kqA & 1) * 4;
    const int offB  = (octB * LOUT + n0B) * 8;

    const int aBase = ((lane >> 4) * BDIM + wr * 32 + (lane & 15)) * 8;
    const int bBase = ((lane >> 4) * LOUT + wc * 112 + (lane & 15)) * 8;

    const float* pA0 = xg + (size_t)rowA0 * (CDIM * LIN);
    const float* pA1 = xg + (size_t)rowA1 * (CDIM * LIN);
    const float* pB  = Wg + n0B;

    // two register stage-sets, STATICALLY indexed (rule #20)
    float a0_[2][4], a1_[2][4], bv_[2][8][2];

    v4f acc[2][7];
    #pragma unroll
    for (int m = 0; m < 2; ++m)
        #pragma unroll
        for (int n = 0; n < 7; ++n)
            acc[m][n] = (v4f){0.f, 0.f, 0.f, 0.f};

// branch-free load of one stage into regset P (valid stages only)
#define LOAD_STAGE(KS, P)                                                       \
    {                                                                           \
        { const float4 v = *reinterpret_cast<const float4*>(pA0 + (KS) + kqA*4);\
          a0_[P][0]=v.x; a0_[P][1]=v.y; a0_[P][2]=v.z; a0_[P][3]=v.w; }         \
        { const float4 v = *reinterpret_cast<const float4*>(pA1 + (KS) + kqA*4);\
          a1_[P][0]=v.x; a1_[P][1]=v.y; a1_[P][2]=v.z; a1_[P][3]=v.w; }         \
        { const float* p = pB + (size_t)((KS) + octB*8) * LOUT;                 \
          _Pragma("unroll")                                                     \
          for (int j = 0; j < 8; ++j) {                                         \
              const float2 v = *reinterpret_cast<const float2*>(p + (size_t)j*LOUT);\
              bv_[P][j][0] = v.x; bv_[P][j][1] = v.y; } }                       \
    }

// clamped-address variant (only stage 22: k >= LIN region); values zeroed at WRITE_SEL
#define LOAD_STAGE_C(KS, P)                                                     \
    {                                                                           \
        const int kA  = (KS) + kqA*4;                                           \
        const int kAc = (kA < LIN) ? kA : (LIN - 4);                            \
        { const float4 v = *reinterpret_cast<const float4*>(pA0 + kAc);         \
          a0_[P][0]=v.x; a0_[P][1]=v.y; a0_[P][2]=v.z; a0_[P][3]=v.w; }         \
        { const float4 v = *reinterpret_cast<const float4*>(pA1 + kAc);         \
          a1_[P][0]=v.x; a1_[P][1]=v.y; a1_[P][2]=v.z; a1_[P][3]=v.w; }         \
        const int kB  = (KS) + octB*8;                                          \
        const int kBc = (kB < LIN) ? kB : (LIN - 8);                            \
        { const float* p = pB + (size_t)kBc * LOUT;                             \
          _Pragma("unroll")                                                     \
          for (int j = 0; j < 8; ++j) {                                         \
              const float2 v = *reinterpret_cast<const float2*>(p + (size_t)j*LOUT);\
              bv_[P][j][0] = v.x; bv_[P][j][1] = v.y; } }                       \
    }

#define WRITE_BODY(P, A0A, A0B, A0C, A0D, A1A, A1B, A1C, A1D, BOK)              \
    {                                                                           \
        uint2 wa; wa.x = pk2(A0A, A0B); wa.y = pk2(A0C, A0D);                   \
        *reinterpret_cast<uint2*>(&Alds[(P)*A_BUF + offA0]) = wa;               \
        uint2 wb; wb.x = pk2(A1A, A1B); wb.y = pk2(A1C, A1D);                   \
        *reinterpret_cast<uint2*>(&Alds[(P)*A_BUF + offA1]) = wb;               \
        uint4 w0;                                                               \
        w0.x = pk2(BOK(0,0), BOK(1,0)); w0.y = pk2(BOK(2,0), BOK(3,0));         \
        w0.z = pk2(BOK(4,0), BOK(5,0)); w0.w = pk2(BOK(6,0), BOK(7,0));         \
        *reinterpret_cast<uint4*>(&Blds[(P)*B_BUF + offB]) = w0;                \
        uint4 w1;                                                               \
        w1.x = pk2(BOK(0,1), BOK(1,1)); w1.y = pk2(BOK(2,1), BOK(3,1));         \
        w1.z = pk2(BOK(4,1), BOK(5,1)); w1.w = pk2(BOK(6,1), BOK(7,1));         \
        *reinterpret_cast<uint4*>(&Blds[(P)*B_BUF + offB + 8]) = w1;            \
    }

#define BRAW(j, h) bv_[PW][j][h]
#define WRITE_STAGE(P)                                                          \
    { enum { PW = (P) };                                                        \
      WRITE_BODY(PW, a0_[PW][0], a0_[PW][1], a0_[PW][2], a0_[PW][3],            \
                     a1_[PW][0], a1_[PW][1], a1_[PW][2], a1_[PW][3], BRAW) }

// stage-22 variant: zero the k>=LIN pads (kq>=4 for A, oct>=2 for B)
#define BSEL(j, h) (bok ? bv_[PW][j][h] : 0.f)
#define WRITE_STAGE_SEL(P)                                                      \
    { enum { PW = (P) };                                                        \
      const bool aok = (kqA < 4); const bool bok = (octB < 2);                  \
      WRITE_BODY(PW, aok ? a0_[PW][0] : 0.f, aok ? a0_[PW][1] : 0.f,            \
                     aok ? a0_[PW][2] : 0.f, aok ? a0_[PW][3] : 0.f,            \
                     aok ? a1_[PW][0] : 0.f, aok ? a1_[PW][1] : 0.f,            \
                     aok ? a1_[PW][2] : 0.f, aok ? a1_[PW][3] : 0.f, BSEL) }

#define MFMA_STAGE(P)                                                           \
    {                                                                           \
        v8s aa0 = *reinterpret_cast<const v8s*>(&Alds[(P)*A_BUF + aBase]);      \
        v8s aa1 = *reinterpret_cast<const v8s*>(&Alds[(P)*A_BUF + aBase + 128]);\
        _Pragma("unroll")                                                       \
        for (int n = 0; n < 7; ++n) {                                           \
            v8s bb = *reinterpret_cast<const v8s*>(&Blds[(P)*B_BUF + bBase + n*128]);\
            acc[0][n] = __builtin_amdgcn_mfma_f32_16x16x32_bf16(aa0, bb, acc[0][n], 0,0,0);\
            acc[1][n] = __builtin_amdgcn_mfma_f32_16x16x32_bf16(aa1, bb, acc[1][n], 0,0,0);\
        }                                                                       \
    }

// LDS-visibility barrier only: vmcnt NOT drained -> in-flight global loads cross
#define BLOCK_SYNC()                                                            \
    {                                                                           \
        asm volatile("s_waitcnt lgkmcnt(0)" ::: "memory");                      \
        __builtin_amdgcn_sched_barrier(0);                                      \
        __builtin_amdgcn_s_barrier();                                           \
        __builtin_amdgcn_sched_barrier(0);                                      \
    }

// steady body: WRITE frees regset Q, LOAD refills it, MFMA overlaps in-flight loads
#define BODY(S, P, Q)                                                           \
    { WRITE_STAGE(Q); LOAD_STAGE(((S)+3)*BK, Q); MFMA_STAGE(P); BLOCK_SYNC(); }

    // ---- prologue: fill both regsets + buf0, keep 2 stages in flight ----
    LOAD_STAGE(0, 0);           // stage 0 -> set0
    LOAD_STAGE(BK, 1);          // stage 1 -> set1
    WRITE_STAGE(0);             // stage 0 -> buf0 (counted vmcnt over set1 loads)
    LOAD_STAGE(2 * BK, 0);      // stage 2 -> set0
    BLOCK_SYNC();

    // ---- steady loop: s = 0..17, branch-free ----
    for (int t = 0; t < 9; ++t) {
        const int s = 2 * t;
        BODY(s, 0, 1);
        BODY(s + 1, 1, 0);
    }
    // ---- peeled tail ----
    // s=18
    { WRITE_STAGE(1); LOAD_STAGE(21 * BK, 1); MFMA_STAGE(0); BLOCK_SYNC(); }
    // s=19 (loads stage 22: clamped addresses)
    { WRITE_STAGE(0); LOAD_STAGE_C(22 * BK, 0); MFMA_STAGE(1); BLOCK_SYNC(); }
    // s=20
    { WRITE_STAGE(1); MFMA_STAGE(0); BLOCK_SYNC(); }
    // s=21 (writes stage 22 with zero-padded k>=720)
    { WRITE_STAGE_SEL(0); MFMA_STAGE(1); BLOCK_SYNC(); }
    // s=22
    { MFMA_STAGE(0); BLOCK_SYNC(); }

    // ---- epilogue: LDS-staged, full-line contiguous stores ----
    float* Lout = reinterpret_cast<float*>(Blds);      // 32x336 fp32 = 43008 B
    const float* bg = bias + (size_t)c * LOUT;
    float* outp = out + (size_t)c * LOUT;

    float biasv[7];
    #pragma unroll
    for (int n = 0; n < 7; ++n) biasv[n] = bg[wc * 112 + n * 16 + (lane & 15)];

    const int rsub = (lane >> 4) * 4;    // row sub-offset within 16-row m-block

    for (int ch = 0; ch < 4; ++ch) {
        if (wr == ch) {   // wave-uniform: 3 waves own this 32-row chunk
            #pragma unroll
            for (int n = 0; n < 7; ++n) {
                const int col = wc * 112 + n * 16 + (lane & 15);
                #pragma unroll
                for (int m = 0; m < 2; ++m) {
                    const int rl0 = m * 16 + rsub;
                    #pragma unroll
                    for (int j = 0; j < 4; ++j)
                        Lout[(rl0 + j) * LOUT + col] = acc[m][n][j] + biasv[n];
                }
            }
        }
        BLOCK_SYNC();
        const int r0 = ch * 32;
        #pragma unroll
        for (int i = 0; i < 7; ++i) {
            const int f2  = i * NTHREADS + tid;     // 0..5375 float2 of chunk
            const int row = f2 / 168;
            const int c2  = f2 % 168;
            const float2 v = *reinterpret_cast<const float2*>(&Lout[f2 * 2]);
            *reinterpret_cast<float2*>(
                outp + ((size_t)(r0 + row) * CDIM) * LOUT + c2 * 2) = v;
        }
        BLOCK_SYNC();
    }
}

extern "C" void kernel_launch(void* const* d_in, const int* in_sizes, int n_in,
                              void* d_out, int out_size, void* d_ws, size_t ws_size,
                              hipStream_t stream) {
    (void)d_ws; (void)ws_size; (void)in_sizes; (void)n_in; (void)out_size;
    const float* x  = (const float*)d_in[0];
    const float* W  = (const float*)d_in[1];
    const float* b  = (const float*)d_in[2];
    float* out      = (float*)d_out;
    grouped_linear_kernel<<<CDIM, NTHREADS, 0, stream>>>(x, W, b, out);
}

// Round 4
// 129.170 us; speedup vs baseline: 1.3059x; 1.3059x over previous
//
#include <hip/hip_runtime.h>

#define BDIM 128
#define CDIM 512
#define LIN  720
#define LOUT 336
#define NTHREADS 768        // 12 waves: 4 (M) x 3 (N)

// LDS geometry (ushort units)
#define ASTAGE 4096         // one 32-k substage of A: [4 oct][128 row][8]
#define ABUF   16384        // one 128-k A super (4 substages)
#define BBUF   10752        // one 32-k B stage: [4 oct][336 col][8]
#define A_TOT  32768        // 2 A supers (double buffer)
#define LDS_BYTES 108544    // (2*ABUF + 2*BBUF) * 2 bytes = 106 KB

typedef short v8s __attribute__((ext_vector_type(8)));  // 8 bf16
typedef float v4f __attribute__((ext_vector_type(4)));  // MFMA acc

__device__ __forceinline__ unsigned short f2bf(float f) {
    unsigned int u = __builtin_bit_cast(unsigned int, f);
    u += 0x7fffu + ((u >> 16) & 1u);
    return (unsigned short)(u >> 16);
}
__device__ __forceinline__ unsigned pk2(float lo, float hi) {
    return (unsigned)f2bf(lo) | ((unsigned)f2bf(hi) << 16);
}
// non-temporal 8B load (W is pure streaming: don't pollute L2)
__device__ __forceinline__ float2 ntld2(const float* p) {
    unsigned long long u = __builtin_nontemporal_load(
        reinterpret_cast<const unsigned long long*>(p));
    return __builtin_bit_cast(float2, u);
}

__global__ __launch_bounds__(NTHREADS, 3)
void grouped_linear_kernel(const float* __restrict__ x,
                           const float* __restrict__ W,
                           const float* __restrict__ bias,
                           float* __restrict__ out)
{
    extern __shared__ unsigned short lds[];
    unsigned short* const Alds = lds;           // [2 buf][4 sub][4 oct][128 row][8]
    unsigned short* const Blds = lds + A_TOT;   // [2 buf][4 oct][336 col][8]

    const int bid  = blockIdx.x;
    // XCD-chunked bijective swizzle (512 = 8*64): consecutive channels on one XCD
    const int c    = ((bid & 7) << 6) | (bid >> 3);
    const int tid  = threadIdx.x;
    const int lane = tid & 63;
    const int wave = tid >> 6;
    const int wr   = wave / 3;   // row tile 0..3 (32 rows)
    const int wc   = wave % 3;   // col tile 0..2 (112 cols)

    const float* xg = x + (size_t)c * LIN;
    const float* Wg = W + (size_t)c * LIN * LOUT;

    // ---- A staging: per 128-k super, 4096 float4 tasks, row-major (q minor)
    // -> each wave instr covers 2 rows x 512B contiguous (page-local requests)
    const int qA  = tid & 31;                  // float4 slot: k_local = 4*qA
    const int r0A = tid >> 5;                  // 0..23
    const int r5A = 120 + ((tid & 255) >> 5);  // rows 120..127 (3x dup, benign)
    const float* pxr[6];
    #pragma unroll
    for (int j = 0; j < 5; ++j) pxr[j] = xg + (size_t)(r0A + 24 * j) * (CDIM * LIN);
    pxr[5] = xg + (size_t)r5A * (CDIM * LIN);

    const int offAq = ((qA >> 3) * ASTAGE) + (((qA & 7) >> 1) << 10) + ((qA & 1) << 2);
    int offAr[6];
    #pragma unroll
    for (int j = 0; j < 5; ++j) offAr[j] = offAq + (r0A + 24 * j) * 8;
    offAr[5] = offAq + r5A * 8;

    // ---- B staging: per 32-k stage, 672 tasks (np, oct), 8 float2 each
    const int tB   = (tid < 672) ? tid : (tid - 96);   // dup tail, benign
    const int npB  = tB % 168;
    const int octB = tB / 168;
    const int n0B  = npB * 2;
    const int offB = (octB * LOUT + n0B) * 8;
    const float* pB = Wg + n0B;

    // ---- MFMA fragment bases
    const int aoffL = ((lane >> 4) << 10) + (wr * 32 + (lane & 15)) * 8;
    const int boffL = ((lane >> 4) * LOUT + wc * 112 + (lane & 15)) * 8;

    float4 ar[6];
    float  bv[8][2];

    v4f acc[2][7];
    #pragma unroll
    for (int m = 0; m < 2; ++m)
        #pragma unroll
        for (int n = 0; n < 7; ++n)
            acc[m][n] = (v4f){0.f, 0.f, 0.f, 0.f};

#define A_LOAD(U)                                                               \
    {                                                                           \
        const int kg = (U) * 128 + 4 * qA;                                      \
        const int kc = (kg <= 716) ? kg : 716;                                  \
        _Pragma("unroll")                                                       \
        for (int j = 0; j < 6; ++j)                                             \
            ar[j] = *reinterpret_cast<const float4*>(pxr[j] + kc);              \
    }

#define A_WRITE(U, BUF)                                                         \
    {                                                                           \
        const bool av = ((U) * 128 + 4 * qA) < 720;                             \
        _Pragma("unroll")                                                       \
        for (int j = 0; j < 6; ++j) {                                           \
            uint2 w;                                                            \
            w.x = pk2(av ? ar[j].x : 0.f, av ? ar[j].y : 0.f);                  \
            w.y = pk2(av ? ar[j].z : 0.f, av ? ar[j].w : 0.f);                  \
            *reinterpret_cast<uint2*>(&Alds[(BUF) * ABUF + offAr[j]]) = w;      \
        }                                                                       \
    }

#define B_LOAD(T)                                                               \
    {                                                                           \
        const int kb = (T) * 32 + octB * 8;                                     \
        const int kc = (kb <= 712) ? kb : 712;                                  \
        const float* p = pB + (size_t)kc * LOUT;                                \
        _Pragma("unroll")                                                       \
        for (int j = 0; j < 8; ++j) {                                           \
            const float2 v = ntld2(p + (size_t)j * LOUT);                       \
            bv[j][0] = v.x; bv[j][1] = v.y;                                     \
        }                                                                       \
    }

#define B_WRITE(T, BUF)                                                         \
    {                                                                           \
        const bool bok = ((T) * 32 + octB * 8) < 720;                           \
        uint4 w0, w1;                                                           \
        w0.x = pk2(bok?bv[0][0]:0.f, bok?bv[1][0]:0.f);                         \
        w0.y = pk2(bok?bv[2][0]:0.f, bok?bv[3][0]:0.f);                         \
        w0.z = pk2(bok?bv[4][0]:0.f, bok?bv[5][0]:0.f);                         \
        w0.w = pk2(bok?bv[6][0]:0.f, bok?bv[7][0]:0.f);                         \
        *reinterpret_cast<uint4*>(&Blds[(BUF) * BBUF + offB]) = w0;             \
        w1.x = pk2(bok?bv[0][1]:0.f, bok?bv[1][1]:0.f);                         \
        w1.y = pk2(bok?bv[2][1]:0.f, bok?bv[3][1]:0.f);                         \
        w1.z = pk2(bok?bv[4][1]:0.f, bok?bv[5][1]:0.f);                         \
        w1.w = pk2(bok?bv[6][1]:0.f, bok?bv[7][1]:0.f);                         \
        *reinterpret_cast<uint4*>(&Blds[(BUF) * BBUF + offB + 8]) = w1;         \
    }

#define MFMA_ST(SUB, AB, BB)                                                    \
    {                                                                           \
        const int ab0 = (AB) * ABUF + (SUB) * ASTAGE + aoffL;                   \
        v8s aa0 = *reinterpret_cast<const v8s*>(&Alds[ab0]);                    \
        v8s aa1 = *reinterpret_cast<const v8s*>(&Alds[ab0 + 128]);              \
        const int bb0 = (BB) * BBUF + boffL;                                    \
        _Pragma("unroll")                                                       \
        for (int n = 0; n < 7; ++n) {                                           \
            v8s bb = *reinterpret_cast<const v8s*>(&Blds[bb0 + n * 128]);       \
            acc[0][n] = __builtin_amdgcn_mfma_f32_16x16x32_bf16(aa0, bb, acc[0][n], 0,0,0); \
            acc[1][n] = __builtin_amdgcn_mfma_f32_16x16x32_bf16(aa1, bb, acc[1][n], 0,0,0); \
        }                                                                       \
    }

// LDS-visibility barrier only: vmcnt NOT drained -> global loads stay in flight
#define BLOCK_SYNC()                                                            \
    {                                                                           \
        asm volatile("s_waitcnt lgkmcnt(0)" ::: "memory");                      \
        __builtin_amdgcn_sched_barrier(0);                                      \
        __builtin_amdgcn_s_barrier();                                           \
        __builtin_amdgcn_sched_barrier(0);                                      \
    }

    // ---- prologue: super 0 + B stages 0,1 ----
    B_LOAD(0); A_LOAD(0);
    B_WRITE(0, 0); A_WRITE(0, 0);
    B_LOAD(1);
    BLOCK_SYNC();

    // ---- main loop: stages 0..19 (supers 0..4); A super u+1 loads at sub2,
    //      writes at sub3, consumed next 4 stages ----
    int abufv = 0;
    #pragma unroll 1
    for (int ss = 0; ss < 20; ss += 4) {
        const int u = ss >> 2;
        B_WRITE(ss + 1, 1); B_LOAD(ss + 2);                MFMA_ST(0, abufv, 0); BLOCK_SYNC();
        B_WRITE(ss + 2, 0); B_LOAD(ss + 3);                MFMA_ST(1, abufv, 1); BLOCK_SYNC();
        B_WRITE(ss + 3, 1); B_LOAD(ss + 4); A_LOAD(u + 1); MFMA_ST(2, abufv, 0); BLOCK_SYNC();
        B_WRITE(ss + 4, 0); B_LOAD(ss + 5); A_WRITE(u + 1, abufv ^ 1);
                                                           MFMA_ST(3, abufv, 1); BLOCK_SYNC();
        abufv ^= 1;
    }

    // ---- tail: stages 20,21,22 (super 5 in buf 1; pads already zeroed) ----
    B_WRITE(21, 1); B_LOAD(22); MFMA_ST(0, 1, 0); BLOCK_SYNC();
    B_WRITE(22, 0);             MFMA_ST(1, 1, 1); BLOCK_SYNC();
                                MFMA_ST(2, 1, 0);

    // ---- epilogue: bias + NT stores (out never re-read) ----
    const float* bg = bias + (size_t)c * LOUT;
    #pragma unroll
    for (int n = 0; n < 7; ++n) {
        const int col = wc * 112 + n * 16 + (lane & 15);
        const float bvs = bg[col];
        #pragma unroll
        for (int m = 0; m < 2; ++m) {
            const int row0 = wr * 32 + m * 16 + ((lane >> 4) << 2);
            #pragma unroll
            for (int j = 0; j < 4; ++j) {
                __builtin_nontemporal_store(acc[m][n][j] + bvs,
                    &out[((size_t)(row0 + j) * CDIM + c) * LOUT + col]);
            }
        }
    }
}

extern "C" void kernel_launch(void* const* d_in, const int* in_sizes, int n_in,
                              void* d_out, int out_size, void* d_ws, size_t ws_size,
                              hipStream_t stream) {
    (void)in_sizes; (void)n_in; (void)out_size; (void)d_ws; (void)ws_size;
    const float* x  = (const float*)d_in[0];
    const float* W  = (const float*)d_in[1];
    const float* b  = (const float*)d_in[2];
    float* out      = (float*)d_out;
    // allow >64KB dynamic LDS (idempotent; host-side, capture-safe)
    hipFuncSetAttribute(reinterpret_cast<const void*>(grouped_linear_kernel),
                        hipFuncAttributeMaxDynamicSharedMemorySize, LDS_BYTES);
    grouped_linear_kernel<<<CDIM, NTHREADS, LDS_BYTES, stream>>>(x, W, b, out);
}